// Round 11
// baseline (561.476 us; speedup 1.0000x reference)
//
#include <hip/hip_runtime.h>
#include <cfloat>
#include <climits>

#define B_   16
#define C_   256
#define K_   1024
#define HW_  4096
#define N_   (B_ * HW_)          // 65536 rows
#define CHW_ (C_ * HW_)          // 1048576

// d_out layout (floats): zq [0, 16777216), seq, losses
#define SEQ_OFF  16777216
#define LOSS_OFF (SEQ_OFF + N_)
// staging inside the zq region (dead after rescue; gather overwrites all):
#define WT_F    0          // w_t f32 [C][K]  (262144 floats) -- diag scratch after rescue
#define WN_F    262144     // wnorm f32 [K]
#define WNU_F   263168     // WNu int [K]  (wn in u-units)
#define WQ_F    264192     // i8 frag-ordered w hi/lo (524288 B = 131072 floats)
#define RLIST_F 395264     // int [131072]
#define RCNT_F  526336     // int
#define WMAX_F  526337     // float (abs-max of w, via atomicMax on bits)

#define RL_CAP  131072
#define EPS_GAP 0.1f
#define XSCL    20.0f
#define XINV    0.05f
#define XOVF    6.3f

typedef int i32x4  __attribute__((ext_vector_type(4)));
typedef int i32x16 __attribute__((ext_vector_type(16)));

__device__ __forceinline__ int pack4b(int b0, int b1, int b2, int b3) {
    return (b0 & 0xFF) | ((b1 & 0xFF) << 8) | ((b2 & 0xFF) << 16) | ((b3 & 0xFF) << 24);
}

// ---------------- prep 0: global abs-max of w ----------------
__global__ __launch_bounds__(256) void wmax_kernel(
    const float* __restrict__ w, unsigned* __restrict__ wmax_bits)
{
    const int tid = blockIdx.x * 256 + threadIdx.x;
    float mx = 0.f;
#pragma unroll
    for (int q = 0; q < 4; ++q) {
        const float4 v = reinterpret_cast<const float4*>(w)[tid * 4 + q];
        mx = fmaxf(mx, fmaxf(fmaxf(fabsf(v.x), fabsf(v.y)), fmaxf(fabsf(v.z), fabsf(v.w))));
    }
#pragma unroll
    for (int m = 1; m < 64; m <<= 1) mx = fmaxf(mx, __shfl_xor(mx, m, 64));
    if ((threadIdx.x & 63) == 0) atomicMax(wmax_bits, __float_as_uint(mx));
}

// ---------------- prep 1: w -> {i8 hi/lo frag-ordered, w_t f32, wn, WNu} ----------------
__global__ __launch_bounds__(256) void wprep_kernel(
    const float* __restrict__ w, const unsigned* __restrict__ wmax_bits,
    unsigned char* __restrict__ wq, float* __restrict__ w_t,
    float* __restrict__ wn, int* __restrict__ wnu)
{
    const int t = threadIdx.x;
    const int l = t & 63;
    const int k = blockIdx.x * 4 + (t >> 6);
    const float wmx = __uint_as_float(*wmax_bits);
    const float s   = 127.4f / wmx;
    const float d1  = wmx / 127.4f;
    const float sl  = s * 256.0f;

    const float4 v4 = *reinterpret_cast<const float4*>(w + (size_t)k * C_ + l * 4);
    float vv[4] = {v4.x, v4.y, v4.z, v4.w};
    float s2 = vv[0]*vv[0] + vv[1]*vv[1] + vv[2]*vv[2] + vv[3]*vv[3];
#pragma unroll
    for (int m = 1; m < 64; m <<= 1) s2 += __shfl_xor(s2, m, 64);

    const int chunk = k >> 5;
    const int col   = k & 31;
#pragma unroll
    for (int q = 0; q < 4; ++q) {
        const int c = l * 4 + q;
        const float v = vv[q];
        const int qh = (int)rintf(v * s);
        const float r = fmaf((float)qh, -d1, v);
        int ql = (int)rintf(r * sl);
        ql = max(-127, min(127, ql));
        const size_t off = (size_t)chunk * 16384 + (size_t)(c >> 5) * 1024
                         + (size_t)((c >> 4) & 1) * 512 + (size_t)col * 16 + (size_t)(c & 15);
        wq[off]        = (unsigned char)(qh & 0xFF);
        wq[off + 8192] = (unsigned char)(ql & 0xFF);
        w_t[(size_t)c * K_ + k] = v;
    }
    if (l == 0) {
        wn[k] = s2;
        wnu[k] = (int)rintf(s2 * (2560.0f / d1));
    }
}

// ---------------- pass A (REAL): barrier-free 1-wave blocks, spill-free ----------------
// r10 structure; only change: __launch_bounds__(64,1) so VGPR is NOT capped at 128
// (r10 spilled: WRITE_SIZE 9 MB). Math/epilogue identical to r6 (validated).
__global__ __launch_bounds__(64, 1) void argmin_i8_kernel(
    const float* __restrict__ x, const unsigned char* __restrict__ wq,
    const int* __restrict__ wnu, const unsigned* __restrict__ wmax_bits,
    float* __restrict__ seq, int* __restrict__ rlist, int* __restrict__ rcount)
{
    const int l = threadIdx.x;
    const int col = l & 31;
    const int khalf = l >> 5;
    const int nb = blockIdx.x;
    const int b  = nb >> 7;
    const int hw0 = (nb & 127) << 5;
    const float* xb = x + (size_t)b * CHW_ + hw0 + col;

    i32x4 ah8[8], al8[8];
    float mx = 0.f;
#pragma unroll
    for (int cc = 0; cc < 8; ++cc) {
        int qh[16], ql[16];
#pragma unroll
        for (int j = 0; j < 16; ++j) {
            const float v = xb[(size_t)(cc * 32 + khalf * 16 + j) * HW_];
            mx = fmaxf(mx, fabsf(v));
            int h = (int)rintf(v * XSCL);
            h = max(-127, min(127, h));
            const float r = fmaf((float)h, -XINV, v);
            int lo = (int)rintf(r * (XSCL * 256.0f));
            lo = max(-127, min(127, lo));
            qh[j] = h; ql[j] = lo;
        }
        ah8[cc] = (i32x4){ pack4b(qh[0],qh[1],qh[2],qh[3]),   pack4b(qh[4],qh[5],qh[6],qh[7]),
                           pack4b(qh[8],qh[9],qh[10],qh[11]), pack4b(qh[12],qh[13],qh[14],qh[15]) };
        al8[cc] = (i32x4){ pack4b(ql[0],ql[1],ql[2],ql[3]),   pack4b(ql[4],ql[5],ql[6],ql[7]),
                           pack4b(ql[8],ql[9],ql[10],ql[11]), pack4b(ql[12],ql[13],ql[14],ql[15]) };
    }

    mx = fmaxf(mx, __shfl_xor(mx, 32, 64));
    if (khalf == 0 && mx > XOVF) {
        const int pos = atomicAdd(rcount, 1);
        if (pos < RL_CAP) rlist[pos] = b * HW_ + hw0 + col;
    }

    const float wmx = __uint_as_float(*wmax_bits);
    const int eps_u = (int)(32614.4f / wmx);

    int m1p[16], m2p[16];
#pragma unroll
    for (int r = 0; r < 16; ++r) { m1p[r] = INT_MAX; m2p[r] = INT_MAX; }

#pragma unroll 1
    for (int ch = 0; ch < 32; ++ch) {
        const unsigned char* base = wq + (size_t)ch * 16384 + l * 16;
        const int wnu_l = wnu[ch * 32 + col];

        i32x16 aH, aX;
#pragma unroll
        for (int r = 0; r < 16; ++r) { aH[r] = 0; aX[r] = 0; }

#pragma unroll
        for (int half = 0; half < 2; ++half) {
            i32x4 bh[4], bl[4];
#pragma unroll
            for (int q = 0; q < 4; ++q) {
                const int ks = half * 4 + q;
                bh[q] = *reinterpret_cast<const i32x4*>(base + ks * 1024);
                bl[q] = *reinterpret_cast<const i32x4*>(base + 8192 + ks * 1024);
            }
#pragma unroll
            for (int q = 0; q < 4; ++q) {
                const int ks = half * 4 + q;
                aH = __builtin_amdgcn_mfma_i32_32x32x32_i8(ah8[ks], bh[q], aH, 0, 0, 0);
                aX = __builtin_amdgcn_mfma_i32_32x32x32_i8(ah8[ks], bl[q], aX, 0, 0, 0);
                aX = __builtin_amdgcn_mfma_i32_32x32x32_i8(al8[ks], bh[q], aX, 0, 0, 0);
            }
        }

#pragma unroll
        for (int r = 0; r < 16; ++r) {
            const int T  = (aH[r] << 8) + aX[r];
            const int D  = wnu_l - T;
            const int Dp = (D & ~31) | ch;
            m2p[r] = min(m2p[r], max(m1p[r], Dp));
            m1p[r] = min(m1p[r], Dp);
        }
    }

    int k1[16];
#pragma unroll
    for (int r = 0; r < 16; ++r) k1[r] = ((m1p[r] & 31) << 5) | col;
#pragma unroll
    for (int mask = 1; mask <= 16; mask <<= 1) {
#pragma unroll
        for (int r = 0; r < 16; ++r) {
            const int om1 = __shfl_xor(m1p[r], mask, 64);
            const int ok1 = __shfl_xor(k1[r],  mask, 64);
            const int om2 = __shfl_xor(m2p[r], mask, 64);
            const int nm2 = min(min(m2p[r], om2), max(m1p[r], om1));
            const bool lt = om1 < m1p[r] || (om1 == m1p[r] && ok1 < k1[r]);
            m1p[r] = lt ? om1 : m1p[r];
            k1[r]  = lt ? ok1 : k1[r];
            m2p[r] = nm2;
        }
    }

    if (col == 0) {
#pragma unroll
        for (int r = 0; r < 16; ++r) {
            const int row_local = (r & 3) + 8 * (r >> 2) + 4 * khalf;
            const int n = b * HW_ + hw0 + row_local;
            seq[n] = (float)k1[r];
            if (m2p[r] - m1p[r] < eps_u) {
                const int pos = atomicAdd(rcount, 1);
                if (pos < RL_CAP) rlist[pos] = n;
            }
        }
    }
}

// ---------------- DIAGNOSTIC variants (write only to dead scratch) ----------------
// MODE 1: loads + epilogue, no MFMA.   MODE 2: MFMA + epilogue, no loads.
// MODE 3: loads + MFMA, no epilogue.   MODE 4: prologue only.
template<int MODE>
__global__ __launch_bounds__(64, 1) void argmin_diag(
    const float* __restrict__ x, const unsigned char* __restrict__ wq,
    const int* __restrict__ wnu, float* __restrict__ scratch)
{
    const int l = threadIdx.x;
    const int col = l & 31;
    const int khalf = l >> 5;
    const int nb = blockIdx.x;
    const int b  = nb >> 7;
    const int hw0 = (nb & 127) << 5;
    const float* xb = x + (size_t)b * CHW_ + hw0 + col;

    i32x4 ah8[8], al8[8];
    float mx = 0.f;
#pragma unroll
    for (int cc = 0; cc < 8; ++cc) {
        int qh[16], ql[16];
#pragma unroll
        for (int j = 0; j < 16; ++j) {
            const float v = xb[(size_t)(cc * 32 + khalf * 16 + j) * HW_];
            mx = fmaxf(mx, fabsf(v));
            int h = (int)rintf(v * XSCL);
            h = max(-127, min(127, h));
            const float r = fmaf((float)h, -XINV, v);
            int lo = (int)rintf(r * (XSCL * 256.0f));
            lo = max(-127, min(127, lo));
            qh[j] = h; ql[j] = lo;
        }
        ah8[cc] = (i32x4){ pack4b(qh[0],qh[1],qh[2],qh[3]),   pack4b(qh[4],qh[5],qh[6],qh[7]),
                           pack4b(qh[8],qh[9],qh[10],qh[11]), pack4b(qh[12],qh[13],qh[14],qh[15]) };
        al8[cc] = (i32x4){ pack4b(ql[0],ql[1],ql[2],ql[3]),   pack4b(ql[4],ql[5],ql[6],ql[7]),
                           pack4b(ql[8],ql[9],ql[10],ql[11]), pack4b(ql[12],ql[13],ql[14],ql[15]) };
    }

    if (MODE == 4) {   // prologue only: keep quantized frags live, exit
#pragma unroll
        for (int cc = 0; cc < 8; ++cc) {
            asm volatile("" :: "v"(ah8[cc][0]), "v"(ah8[cc][3]),
                              "v"(al8[cc][0]), "v"(al8[cc][3]));
        }
        scratch[(size_t)nb * 64 + l] = mx;
        return;
    }

    int m1p[16], m2p[16];
#pragma unroll
    for (int r = 0; r < 16; ++r) { m1p[r] = INT_MAX; m2p[r] = INT_MAX; }

#pragma unroll 1
    for (int ch = 0; ch < 32; ++ch) {
        const unsigned char* base = wq + (size_t)ch * 16384 + l * 16;
        const int wnu_l = wnu[ch * 32 + col];

        i32x16 aH, aX;
#pragma unroll
        for (int r = 0; r < 16; ++r) { aH[r] = 0; aX[r] = 0; }
        int Tload = 0;

#pragma unroll
        for (int half = 0; half < 2; ++half) {
            i32x4 bh[4], bl[4];
            if (MODE != 2) {
#pragma unroll
                for (int q = 0; q < 4; ++q) {
                    const int ks = half * 4 + q;
                    bh[q] = *reinterpret_cast<const i32x4*>(base + ks * 1024);
                    bl[q] = *reinterpret_cast<const i32x4*>(base + 8192 + ks * 1024);
                }
            } else {   // synth fragments: cheap, ch-dependent (not hoistable)
#pragma unroll
                for (int q = 0; q < 4; ++q) {
                    const int s0 = (int)((unsigned)l * 0x9E3779B9u) ^ (ch * 4 + q);
                    bh[q] = (i32x4){ s0, s0 + 1, s0 + 2, s0 + 3 };
                    bl[q] = (i32x4){ s0 ^ 0x55, s0 ^ 0xAA, s0 + 7, s0 - 7 };
                }
            }
            if (MODE == 1) {   // keep loads live, skip MFMA; fold loads into epilogue input
#pragma unroll
                for (int q = 0; q < 4; ++q) Tload += bh[q][0] + bl[q][0];
            } else {
#pragma unroll
                for (int q = 0; q < 4; ++q) {
                    const int ks = half * 4 + q;
                    aH = __builtin_amdgcn_mfma_i32_32x32x32_i8(ah8[ks], bh[q], aH, 0, 0, 0);
                    aX = __builtin_amdgcn_mfma_i32_32x32x32_i8(ah8[ks], bl[q], aX, 0, 0, 0);
                    aX = __builtin_amdgcn_mfma_i32_32x32x32_i8(al8[ks], bh[q], aX, 0, 0, 0);
                }
            }
        }

        if (MODE == 3) {   // keep MFMA chains live, skip epilogue
            asm volatile("" :: "v"(aH[0]), "v"(aH[15]), "v"(aX[0]), "v"(aX[15]));
            m1p[0] = min(m1p[0], aH[0] ^ ch);
        } else {
#pragma unroll
            for (int r = 0; r < 16; ++r) {
                const int T  = (MODE == 1) ? (Tload + r) : ((aH[r] << 8) + aX[r]);
                const int D  = wnu_l - T;
                const int Dp = (D & ~31) | ch;
                m2p[r] = min(m2p[r], max(m1p[r], Dp));
                m1p[r] = min(m1p[r], Dp);
            }
        }
    }

    int acc = 0;
#pragma unroll
    for (int r = 0; r < 16; ++r) acc ^= m1p[r] ^ m2p[r];
    scratch[(size_t)nb * 64 + l] = (float)acc;
}

// ---------------- rescue: exact f32 re-argmin for flagged rows ----------------
__global__ __launch_bounds__(256) void rescue_kernel(
    const float* __restrict__ x, const float* __restrict__ w_t,
    const float* __restrict__ wnorm, const int* __restrict__ rlist,
    const int* __restrict__ rcount, float* __restrict__ seq)
{
    __shared__ float xr[C_];
    __shared__ float bvs[4];
    __shared__ int   bis[4];
    const int t = threadIdx.x;
    const int cnt = min(*rcount, RL_CAP);
    for (int ii = blockIdx.x; ii < cnt; ii += gridDim.x) {
        const int n = rlist[ii];
        const int b = n >> 12, hw = n & 4095;
        xr[t] = x[(size_t)b * CHW_ + (size_t)t * HW_ + hw];
        __syncthreads();
        float best = FLT_MAX; int bidx = 0;
#pragma unroll
        for (int q = 0; q < 4; ++q) {
            const int k = t + q * 256;
            float acc = 0.f;
            for (int c = 0; c < C_; ++c) acc = fmaf(xr[c], w_t[(size_t)c * K_ + k], acc);
            const float d = wnorm[k] - 2.f * acc;
            if (d < best || (d == best && k < bidx)) { best = d; bidx = k; }
        }
#pragma unroll
        for (int mask = 1; mask < 64; mask <<= 1) {
            const float ov = __shfl_xor(best, mask, 64);
            const int   oi = __shfl_xor(bidx, mask, 64);
            if (ov < best || (ov == best && oi < bidx)) { best = ov; bidx = oi; }
        }
        if ((t & 63) == 0) { bvs[t >> 6] = best; bis[t >> 6] = bidx; }
        __syncthreads();
        if (t == 0) {
            float bv = bvs[0]; int bi = bis[0];
#pragma unroll
            for (int w2 = 1; w2 < 4; ++w2)
                if (bvs[w2] < bv || (bvs[w2] == bv && bis[w2] < bi)) { bv = bvs[w2]; bi = bis[w2]; }
            seq[n] = (float)bi;
        }
        __syncthreads();
    }
}

// ---------------- gather z, write zq, accumulate loss ----------------
__global__ __launch_bounds__(256) void gather_kernel(
    const float* __restrict__ x, const float* __restrict__ w,
    const float* __restrict__ seqf, float* __restrict__ zq,
    double* __restrict__ loss_acc)
{
    __shared__ float ws[C_ * 64];
    const int t   = threadIdx.x;
    const int nb  = blockIdx.x;
    const int b   = nb >> 6;
    const int hw0 = (nb & 63) << 6;
    {
        const int j = t >> 2, q = t & 3;
        const int idx = (int)seqf[b * HW_ + hw0 + j];
        const float* wrow = w + (size_t)idx * C_ + q * 64;
#pragma unroll
        for (int m = 0; m < 16; ++m) {
            const float4 v = *reinterpret_cast<const float4*>(wrow + m * 4);
            const int c = q * 64 + m * 4;
            ws[(c + 0) * 64 + j] = v.x;
            ws[(c + 1) * 64 + j] = v.y;
            ws[(c + 2) * 64 + j] = v.z;
            ws[(c + 3) * 64 + j] = v.w;
        }
    }
    __syncthreads();
    const int r  = t & 63;
    const int cg = t >> 6;
    const float* xb = x  + (size_t)b * CHW_ + hw0;
    float*       zb = zq + (size_t)b * CHW_ + hw0;
    float lsum = 0.f;
#pragma unroll 4
    for (int cc = 0; cc < 64; ++cc) {
        const int c = cg * 64 + cc;
        const float xv = xb[(size_t)c * HW_ + r];
        const float d  = ws[c * 64 + r] - xv;
        zb[(size_t)c * HW_ + r] = xv + d;
        lsum += d * d;
    }
#pragma unroll
    for (int off = 32; off >= 1; off >>= 1) lsum += __shfl_down(lsum, off, 64);
    __syncthreads();
    if ((t & 63) == 0) ws[t >> 6] = lsum;
    __syncthreads();
    if (t == 0)
        atomicAdd(loss_acc, (double)(ws[0] + ws[1] + ws[2] + ws[3]));
}

__global__ void finalize_kernel(const double* __restrict__ acc, float* __restrict__ loss_out)
{
    const double s = *acc;
    const float m = (float)(s / (double)((size_t)N_ * C_));
    loss_out[0] = m;
    loss_out[1] = m;
}

extern "C" void kernel_launch(void* const* d_in, const int* in_sizes, int n_in,
                              void* d_out, int out_size, void* d_ws, size_t ws_size,
                              hipStream_t stream)
{
    (void)in_sizes; (void)n_in; (void)out_size; (void)d_ws; (void)ws_size;
    const float* x = (const float*)d_in[0];
    const float* w = (const float*)d_in[1];
    float* out = (float*)d_out;

    float*         w_t    = out + WT_F;
    float*         wn     = out + WN_F;
    int*           wnu    = (int*)(out + WNU_F);
    unsigned char* wq     = (unsigned char*)(out + WQ_F);
    int*           rlist  = (int*)(out + RLIST_F);
    int*           rcount = (int*)(out + RCNT_F);
    unsigned*      wmaxb  = (unsigned*)(out + WMAX_F);
    float*         seq    = out + SEQ_OFF;
    double*        loss_acc = (double*)(out + LOSS_OFF);
    float*         dscr   = out + WT_F;      // diag scratch: w_t region (dead after rescue)

    hipMemsetAsync((void*)wmaxb, 0, 4, stream);
    hipMemsetAsync((void*)rcount, 0, 4, stream);
    wmax_kernel<<<64, 256, 0, stream>>>(w, wmaxb);
    wprep_kernel<<<256, 256, 0, stream>>>(w, wmaxb, wq, w_t, wn, wnu);
    argmin_i8_kernel<<<2048, 64, 0, stream>>>(x, wq, wnu, wmaxb, seq, rlist, rcount);
    rescue_kernel<<<1024, 256, 0, stream>>>(x, w_t, wn, rlist, rcount, seq);
    // ---- diagnostics (outputs dead; timing/counters only) ----
    argmin_diag<1><<<2048, 64, 0, stream>>>(x, wq, wnu, dscr);   // loads+epi, no MFMA
    argmin_diag<2><<<2048, 64, 0, stream>>>(x, wq, wnu, dscr);   // MFMA+epi, no loads
    argmin_diag<3><<<2048, 64, 0, stream>>>(x, wq, wnu, dscr);   // loads+MFMA, no epi
    argmin_diag<4><<<2048, 64, 0, stream>>>(x, wq, wnu, dscr);   // prologue only
    hipMemsetAsync((char*)d_out + (size_t)LOSS_OFF * 4, 0, 8, stream);
    gather_kernel<<<1024, 256, 0, stream>>>(x, w, seq, out, loss_acc);
    finalize_kernel<<<1, 1, 0, stream>>>(loss_acc, out + LOSS_OFF);
}

// Round 12
// 191.487 us; speedup vs baseline: 2.9322x; 2.9322x over previous
//
#include <hip/hip_runtime.h>
#include <cfloat>
#include <climits>

#define B_   16
#define C_   256
#define K_   1024
#define HW_  4096
#define N_   (B_ * HW_)          // 65536 rows
#define CHW_ (C_ * HW_)          // 1048576

// d_out layout (floats): zq [0, 16777216), seq, losses
#define SEQ_OFF  16777216
#define LOSS_OFF (SEQ_OFF + N_)
// staging inside the zq region (dead after rescue; gather overwrites all):
#define WT_F    0          // w_t f32 [C][K]          (262144 floats)
#define WN_F    262144     // wnorm f32 [K]
#define WNU_F   263168     // WNu int [K]  (wn in u-units)
#define WQ_F    264192     // i8 frag-ordered w hi/lo (524288 B)
#define RLIST_F 395264     // int [131072]
#define RCNT_F  526336     // int
#define WMAX_F  526337     // float (abs-max of w, via atomicMax on bits)

#define RL_CAP  131072
#define EPS_GAP 0.1f
#define XSCL    20.0f
#define XINV    0.05f
#define XOVF    6.3f

typedef int i32x4 __attribute__((ext_vector_type(4)));

__device__ __forceinline__ int pack4b(int b0, int b1, int b2, int b3) {
    return (b0 & 0xFF) | ((b1 & 0xFF) << 8) | ((b2 & 0xFF) << 16) | ((b3 & 0xFF) << 24);
}

// ---------------- prep 0: global abs-max of w ----------------
__global__ __launch_bounds__(256) void wmax_kernel(
    const float* __restrict__ w, unsigned* __restrict__ wmax_bits)
{
    const int tid = blockIdx.x * 256 + threadIdx.x;
    float mx = 0.f;
#pragma unroll
    for (int q = 0; q < 4; ++q) {
        const float4 v = reinterpret_cast<const float4*>(w)[tid * 4 + q];
        mx = fmaxf(mx, fmaxf(fmaxf(fabsf(v.x), fabsf(v.y)), fmaxf(fabsf(v.z), fabsf(v.w))));
    }
#pragma unroll
    for (int m = 1; m < 64; m <<= 1) mx = fmaxf(mx, __shfl_xor(mx, m, 64));
    if ((threadIdx.x & 63) == 0) atomicMax(wmax_bits, __float_as_uint(mx));
}

// ---------------- prep 1: w -> {i8 hi/lo 16x16x64-frag-ordered, w_t f32, wn, WNu} ----------
// New layout for mfma_i32_16x16x64_i8, chunk = 16 codes = 8KB block [hi 4K | lo 4K]:
// code k, channel c: off = (k>>4)*8192 + tier*4096 + (c>>6)*1024 + ((c>>4)&3)*256
//                          + (k&15)*16 + (c&15)
// so a B-fragment read for (chunk, step s) is one dwordx4 at  base + s*1024 + l*16
// (lane l: col=l&15, kgrp=l>>4; 16 bytes are 16 consecutive K elements).
__global__ __launch_bounds__(256) void wprep_kernel(
    const float* __restrict__ w, const unsigned* __restrict__ wmax_bits,
    unsigned char* __restrict__ wq, float* __restrict__ w_t,
    float* __restrict__ wn, int* __restrict__ wnu)
{
    const int t = threadIdx.x;
    const int l = t & 63;
    const int k = blockIdx.x * 4 + (t >> 6);   // one wave per code
    const float wmx = __uint_as_float(*wmax_bits);
    const float s   = 127.4f / wmx;
    const float d1  = wmx / 127.4f;
    const float sl  = s * 256.0f;

    const float4 v4 = *reinterpret_cast<const float4*>(w + (size_t)k * C_ + l * 4);
    float vv[4] = {v4.x, v4.y, v4.z, v4.w};
    float s2 = vv[0]*vv[0] + vv[1]*vv[1] + vv[2]*vv[2] + vv[3]*vv[3];
#pragma unroll
    for (int m = 1; m < 64; m <<= 1) s2 += __shfl_xor(s2, m, 64);

    const int chunk = k >> 4;
    const int col   = k & 15;
#pragma unroll
    for (int q = 0; q < 4; ++q) {
        const int c = l * 4 + q;
        const float v = vv[q];
        const int qh = (int)rintf(v * s);
        const float r = fmaf((float)qh, -d1, v);
        int ql = (int)rintf(r * sl);
        ql = max(-127, min(127, ql));
        const size_t off = (size_t)chunk * 8192 + (size_t)(c >> 6) * 1024
                         + (size_t)((c >> 4) & 3) * 256 + (size_t)col * 16 + (size_t)(c & 15);
        wq[off]        = (unsigned char)(qh & 0xFF);
        wq[off + 4096] = (unsigned char)(ql & 0xFF);
        w_t[(size_t)c * K_ + k] = v;
    }
    if (l == 0) {
        wn[k] = s2;
        wnu[k] = (int)rintf(s2 * (2560.0f / d1));   // u-units, u = d1/2560 (r6-validated)
    }
}

// ---------------- pass A: 16x16x64 i8 MFMA argmin, 6 short chains, no LDS/barriers -------
// 2048 blocks x 64 threads (1 wave = 32 rows as two 16-row tiles sharing B).
// Per 16-code chunk: 8 dwordx4 L2 loads, 24 MFMA across 6 independent 4-deep chains,
// packed-int min1/min2 with 6-bit chunk id. (64,2): <=256 unified regs, no spill,
// 2 waves/SIMD guaranteed. Math in u-units identical to r6 (validated).
__global__ __launch_bounds__(64, 2) void argmin_i8_kernel(
    const float* __restrict__ x, const unsigned char* __restrict__ wq,
    const int* __restrict__ wnu, const unsigned* __restrict__ wmax_bits,
    float* __restrict__ seq, int* __restrict__ rlist, int* __restrict__ rcount)
{
    const int l   = threadIdx.x;
    const int col = l & 15;          // A-row within tile / B-col / D-col
    const int kg  = l >> 4;          // k-group 0..3 (16 K-elems each)
    const int nb  = blockIdx.x;
    const int b   = nb >> 7;
    const int hw0 = (nb & 127) << 5;
    const float* xb = x + (size_t)b * CHW_ + hw0;

    // ---- x direct load + two-level i8 quantization, 2 tiles x 4 K-steps ----
    i32x4 ah[2][4], al[2][4];
    float mxr[2] = {0.f, 0.f};
#pragma unroll
    for (int t = 0; t < 2; ++t) {
        const int row = t * 16 + col;
#pragma unroll
        for (int s = 0; s < 4; ++s) {
            int qh[16], ql[16];
#pragma unroll
            for (int j = 0; j < 16; ++j) {
                const float v = xb[(size_t)(s * 64 + kg * 16 + j) * HW_ + row];
                mxr[t] = fmaxf(mxr[t], fabsf(v));
                int h = (int)rintf(v * XSCL);
                h = max(-127, min(127, h));
                const float r = fmaf((float)h, -XINV, v);
                int lo = (int)rintf(r * (XSCL * 256.0f));
                lo = max(-127, min(127, lo));
                qh[j] = h; ql[j] = lo;
            }
            ah[t][s] = (i32x4){ pack4b(qh[0],qh[1],qh[2],qh[3]),   pack4b(qh[4],qh[5],qh[6],qh[7]),
                                pack4b(qh[8],qh[9],qh[10],qh[11]), pack4b(qh[12],qh[13],qh[14],qh[15]) };
            al[t][s] = (i32x4){ pack4b(ql[0],ql[1],ql[2],ql[3]),   pack4b(ql[4],ql[5],ql[6],ql[7]),
                                pack4b(ql[8],ql[9],ql[10],ql[11]), pack4b(ql[12],ql[13],ql[14],ql[15]) };
        }
    }

    // overflow rows: reduce each tile's channel-max over the 4 kg lane-groups (bits 4,5)
#pragma unroll
    for (int t = 0; t < 2; ++t) {
        mxr[t] = fmaxf(mxr[t], __shfl_xor(mxr[t], 16, 64));
        mxr[t] = fmaxf(mxr[t], __shfl_xor(mxr[t], 32, 64));
        if (kg == 0 && mxr[t] > XOVF) {
            const int pos = atomicAdd(rcount, 1);
            if (pos < RL_CAP) rlist[pos] = b * HW_ + hw0 + t * 16 + col;
        }
    }

    const float wmx = __uint_as_float(*wmax_bits);
    const int eps_u = (int)(32614.4f / wmx);   // EPS_GAP * 2560 * 127.4 / wmax

    int m1p[2][4], m2p[2][4];
#pragma unroll
    for (int t = 0; t < 2; ++t)
#pragma unroll
        for (int i = 0; i < 4; ++i) { m1p[t][i] = INT_MAX; m2p[t][i] = INT_MAX; }

#pragma unroll 1
    for (int ch = 0; ch < 64; ++ch) {
        const unsigned char* base = wq + (size_t)ch * 8192 + l * 16;
        const int wnu_l = wnu[ch * 16 + col];

        // batch the chunk's 8 independent L2 loads
        i32x4 bh[4], bl[4];
#pragma unroll
        for (int s = 0; s < 4; ++s) {
            bh[s] = *reinterpret_cast<const i32x4*>(base + s * 1024);
            bl[s] = *reinterpret_cast<const i32x4*>(base + 4096 + s * 1024);
        }

        // 6 independent accumulator chains, each 4-deep
        i32x4 aH0 = {0,0,0,0}, aH1 = {0,0,0,0};
        i32x4 aXa0 = {0,0,0,0}, aXb0 = {0,0,0,0};
        i32x4 aXa1 = {0,0,0,0}, aXb1 = {0,0,0,0};
#pragma unroll
        for (int s = 0; s < 4; ++s) {
            aH0  = __builtin_amdgcn_mfma_i32_16x16x64_i8(ah[0][s], bh[s], aH0, 0, 0, 0);
            aH1  = __builtin_amdgcn_mfma_i32_16x16x64_i8(ah[1][s], bh[s], aH1, 0, 0, 0);
            aXa0 = __builtin_amdgcn_mfma_i32_16x16x64_i8(ah[0][s], bl[s], aXa0, 0, 0, 0);
            aXb0 = __builtin_amdgcn_mfma_i32_16x16x64_i8(al[0][s], bh[s], aXb0, 0, 0, 0);
            aXa1 = __builtin_amdgcn_mfma_i32_16x16x64_i8(ah[1][s], bl[s], aXa1, 0, 0, 0);
            aXb1 = __builtin_amdgcn_mfma_i32_16x16x64_i8(al[1][s], bh[s], aXb1, 0, 0, 0);
        }

        // D = WNu - (aH*256 + aX); pack 6-bit chunk id in LSBs; min1/min2 update
#pragma unroll
        for (int i = 0; i < 4; ++i) {
            const int T0  = (aH0[i] << 8) + aXa0[i] + aXb0[i];
            const int D0  = wnu_l - T0;
            const int Dp0 = (D0 & ~63) | ch;
            m2p[0][i] = min(m2p[0][i], max(m1p[0][i], Dp0));
            m1p[0][i] = min(m1p[0][i], Dp0);
            const int T1  = (aH1[i] << 8) + aXa1[i] + aXb1[i];
            const int D1  = wnu_l - T1;
            const int Dp1 = (D1 & ~63) | ch;
            m2p[1][i] = min(m2p[1][i], max(m1p[1][i], Dp1));
            m1p[1][i] = min(m1p[1][i], Dp1);
        }
    }

    // rebuild k = (chunk<<4)|col, merge across the 16 code-lanes (lane bits 0..3)
    int k1[2][4];
#pragma unroll
    for (int t = 0; t < 2; ++t)
#pragma unroll
        for (int i = 0; i < 4; ++i) k1[t][i] = ((m1p[t][i] & 63) << 4) | col;
#pragma unroll
    for (int mask = 1; mask <= 8; mask <<= 1) {
#pragma unroll
        for (int t = 0; t < 2; ++t) {
#pragma unroll
            for (int i = 0; i < 4; ++i) {
                const int om1 = __shfl_xor(m1p[t][i], mask, 64);
                const int ok1 = __shfl_xor(k1[t][i],  mask, 64);
                const int om2 = __shfl_xor(m2p[t][i], mask, 64);
                const int nm2 = min(min(m2p[t][i], om2), max(m1p[t][i], om1));
                const bool lt = om1 < m1p[t][i] || (om1 == m1p[t][i] && ok1 < k1[t][i]);
                m1p[t][i] = lt ? om1 : m1p[t][i];
                k1[t][i]  = lt ? ok1 : k1[t][i];
                m2p[t][i] = nm2;
            }
        }
    }

    // writers: col==0 lanes (l = 0,16,32,48); lane kg holds rows kg*4+i of each tile
    if (col == 0) {
#pragma unroll
        for (int t = 0; t < 2; ++t) {
#pragma unroll
            for (int i = 0; i < 4; ++i) {
                const int row_local = t * 16 + kg * 4 + i;   // 0..31
                const int n = b * HW_ + hw0 + row_local;
                seq[n] = (float)k1[t][i];
                if (m2p[t][i] - m1p[t][i] < eps_u) {
                    const int pos = atomicAdd(rcount, 1);
                    if (pos < RL_CAP) rlist[pos] = n;
                }
            }
        }
    }
}

// ---------------- rescue: exact f32 re-argmin for flagged rows ----------------
__global__ __launch_bounds__(256) void rescue_kernel(
    const float* __restrict__ x, const float* __restrict__ w_t,
    const float* __restrict__ wnorm, const int* __restrict__ rlist,
    const int* __restrict__ rcount, float* __restrict__ seq)
{
    __shared__ float xr[C_];
    __shared__ float bvs[4];
    __shared__ int   bis[4];
    const int t = threadIdx.x;
    const int cnt = min(*rcount, RL_CAP);
    for (int ii = blockIdx.x; ii < cnt; ii += gridDim.x) {
        const int n = rlist[ii];
        const int b = n >> 12, hw = n & 4095;
        xr[t] = x[(size_t)b * CHW_ + (size_t)t * HW_ + hw];
        __syncthreads();
        float best = FLT_MAX; int bidx = 0;
#pragma unroll
        for (int q = 0; q < 4; ++q) {
            const int k = t + q * 256;
            float acc = 0.f;
            for (int c = 0; c < C_; ++c) acc = fmaf(xr[c], w_t[(size_t)c * K_ + k], acc);
            const float d = wnorm[k] - 2.f * acc;
            if (d < best || (d == best && k < bidx)) { best = d; bidx = k; }
        }
#pragma unroll
        for (int mask = 1; mask < 64; mask <<= 1) {
            const float ov = __shfl_xor(best, mask, 64);
            const int   oi = __shfl_xor(bidx, mask, 64);
            if (ov < best || (ov == best && oi < bidx)) { best = ov; bidx = oi; }
        }
        if ((t & 63) == 0) { bvs[t >> 6] = best; bis[t >> 6] = bidx; }
        __syncthreads();
        if (t == 0) {
            float bv = bvs[0]; int bi = bis[0];
#pragma unroll
            for (int w2 = 1; w2 < 4; ++w2)
                if (bvs[w2] < bv || (bvs[w2] == bv && bis[w2] < bi)) { bv = bvs[w2]; bi = bis[w2]; }
            seq[n] = (float)bi;
        }
        __syncthreads();
    }
}

// ---------------- gather z (via LDS-staged w rows), write zq, accumulate loss ----------------
__global__ __launch_bounds__(256) void gather_kernel(
    const float* __restrict__ x, const float* __restrict__ w,
    const float* __restrict__ seqf, float* __restrict__ zq,
    double* __restrict__ loss_acc)
{
    __shared__ float ws[C_ * 64];
    const int t   = threadIdx.x;
    const int nb  = blockIdx.x;
    const int b   = nb >> 6;
    const int hw0 = (nb & 63) << 6;
    {
        const int j = t >> 2, q = t & 3;
        const int idx = (int)seqf[b * HW_ + hw0 + j];
        const float* wrow = w + (size_t)idx * C_ + q * 64;
#pragma unroll
        for (int m = 0; m < 16; ++m) {
            const float4 v = *reinterpret_cast<const float4*>(wrow + m * 4);
            const int c = q * 64 + m * 4;
            ws[(c + 0) * 64 + j] = v.x;
            ws[(c + 1) * 64 + j] = v.y;
            ws[(c + 2) * 64 + j] = v.z;
            ws[(c + 3) * 64 + j] = v.w;
        }
    }
    __syncthreads();
    const int r  = t & 63;
    const int cg = t >> 6;
    const float* xb = x  + (size_t)b * CHW_ + hw0;
    float*       zb = zq + (size_t)b * CHW_ + hw0;
    float lsum = 0.f;
#pragma unroll 4
    for (int cc = 0; cc < 64; ++cc) {
        const int c = cg * 64 + cc;
        const float xv = xb[(size_t)c * HW_ + r];
        const float d  = ws[c * 64 + r] - xv;
        zb[(size_t)c * HW_ + r] = xv + d;
        lsum += d * d;
    }
#pragma unroll
    for (int off = 32; off >= 1; off >>= 1) lsum += __shfl_down(lsum, off, 64);
    __syncthreads();
    if ((t & 63) == 0) ws[t >> 6] = lsum;
    __syncthreads();
    if (t == 0)
        atomicAdd(loss_acc, (double)(ws[0] + ws[1] + ws[2] + ws[3]));
}

__global__ void finalize_kernel(const double* __restrict__ acc, float* __restrict__ loss_out)
{
    const double s = *acc;
    const float m = (float)(s / (double)((size_t)N_ * C_));
    loss_out[0] = m;
    loss_out[1] = m;
}

extern "C" void kernel_launch(void* const* d_in, const int* in_sizes, int n_in,
                              void* d_out, int out_size, void* d_ws, size_t ws_size,
                              hipStream_t stream)
{
    (void)in_sizes; (void)n_in; (void)out_size; (void)d_ws; (void)ws_size;
    const float* x = (const float*)d_in[0];
    const float* w = (const float*)d_in[1];
    float* out = (float*)d_out;

    float*         w_t    = out + WT_F;
    float*         wn     = out + WN_F;
    int*           wnu    = (int*)(out + WNU_F);
    unsigned char* wq     = (unsigned char*)(out + WQ_F);
    int*           rlist  = (int*)(out + RLIST_F);
    int*           rcount = (int*)(out + RCNT_F);
    unsigned*      wmaxb  = (unsigned*)(out + WMAX_F);
    float*         seq    = out + SEQ_OFF;
    double*        loss_acc = (double*)(out + LOSS_OFF);

    hipMemsetAsync((void*)wmaxb, 0, 4, stream);
    hipMemsetAsync((void*)rcount, 0, 4, stream);
    wmax_kernel<<<64, 256, 0, stream>>>(w, wmaxb);
    wprep_kernel<<<256, 256, 0, stream>>>(w, wmaxb, wq, w_t, wn, wnu);
    argmin_i8_kernel<<<2048, 64, 0, stream>>>(x, wq, wnu, wmaxb, seq, rlist, rcount);
    rescue_kernel<<<1024, 256, 0, stream>>>(x, w_t, wn, rlist, rcount, seq);
    hipMemsetAsync((char*)d_out + (size_t)LOSS_OFF * 4, 0, 8, stream);
    gather_kernel<<<1024, 256, 0, stream>>>(x, w, seq, out, loss_acc);
    finalize_kernel<<<1, 1, 0, stream>>>(loss_acc, out + LOSS_OFF);
}